// Round 1
// baseline (11326.934 us; speedup 1.0000x reference)
//
#include <hip/hip_runtime.h>

#define NCLS   20
#define NB     8
#define MAXDET 300
#define NEGV   (-1e9f)
#define NEGH   (-5e8f)   /* NEG/2 */
#define NPT    48
#define BLK    1024

// ---------------- Kernel 1: per (b,c) greedy NMS, reference-exact ----------------
__global__ __launch_bounds__(BLK, 4) void nms_pair_kernel(
    const float4* __restrict__ boxes,   // [B, N] of float4
    const float*  __restrict__ cls,     // [B, N, C]
    float* __restrict__ sel_ws,         // [B*C, MAXDET]
    int*   __restrict__ idx_ws,         // [B*C, MAXDET]
    int n)
{
    const int pair = blockIdx.x;        // b*NCLS + c
    const int b = pair / NCLS;
    const int c = pair % NCLS;
    const int tid = threadIdx.x;

    const float4* bb = boxes + (long)b * n;
    const float*  cb = cls + (long)b * n * NCLS + c;

    float s[NPT];
    float lmax = NEGV; int lidx = 0x7fffffff;
#pragma unroll
    for (int t = 0; t < NPT; ++t) {
        int j = t * BLK + tid;
        float v = NEGV;
        if (j < n) {
            float sc = cb[(long)j * NCLS];
            if (sc > 0.05f) v = sc;          // strict >, like reference
        }
        s[t] = v;
        if (v > lmax) { lmax = v; lidx = j; }  // j ascending in t -> first occurrence kept
    }

    __shared__ float rs[16];
    __shared__ int   ri[16];
    __shared__ float bs_s;
    __shared__ int   bi_s;

    float* selp = sel_ws + pair * MAXDET;
    int*   idxp = idx_ws + pair * MAXDET;

    for (int k = 0; k < MAXDET; ++k) {
        // ---- block argmax reduce (tie -> lowest index, matching jnp.argmax) ----
        float rv = lmax; int rix = lidx;
#pragma unroll
        for (int off = 32; off > 0; off >>= 1) {
            float ov = __shfl_xor(rv, off);
            int   oi = __shfl_xor(rix, off);
            if (ov > rv || (ov == rv && oi < rix)) { rv = ov; rix = oi; }
        }
        if ((tid & 63) == 0) { rs[tid >> 6] = rv; ri[tid >> 6] = rix; }
        __syncthreads();
        if (tid < 64) {
            float v2 = (tid < 16) ? rs[tid] : NEGV;
            int   i2 = (tid < 16) ? ri[tid] : 0x7fffffff;
#pragma unroll
            for (int off = 8; off > 0; off >>= 1) {
                float ov = __shfl_xor(v2, off);
                int   oi = __shfl_xor(i2, off);
                if (ov > v2 || (ov == v2 && oi < i2)) { v2 = ov; i2 = oi; }
            }
            if (tid == 0) { bs_s = v2; bi_s = i2; }
        }
        __syncthreads();
        const float smax = bs_s;
        const int   imax = bi_s;

        if (smax <= NEGH) {
            // no valid candidates remain: every further iteration is invalid
            for (int f = k + tid; f < MAXDET; f += BLK) { selp[f] = NEGV; idxp[f] = 0; }
            break;
        }
        if (tid == 0) { selp[k] = smax; idxp[k] = imax; }

        const float4 bi4 = bb[imax];                       // broadcast load
        const float area_i = (bi4.z - bi4.x) * (bi4.w - bi4.y);

        // ---- suppression pass fused with next-iteration local argmax ----
        lmax = NEGV; lidx = 0x7fffffff;
#pragma unroll
        for (int t = 0; t < NPT; ++t) {
            if (s[t] > NEGH) {
                int j = t * BLK + tid;
                float4 bj = bb[j];
                float ltx = fmaxf(bi4.x, bj.x);
                float lty = fmaxf(bi4.y, bj.y);
                float rbx = fminf(bi4.z, bj.z);
                float rby = fminf(bi4.w, bj.w);
                float wx = fmaxf(rbx - ltx, 0.0f);
                float wy = fmaxf(rby - lty, 0.0f);
                float inter = wx * wy;
                float area_j = (bj.z - bj.x) * (bj.w - bj.y);
                float den = area_j + area_i - inter + 1e-9f;  // ((aj+ai)-inter)+1e-9, same order as ref
                float iou = inter / den;                      // IEEE fp32 divide, matches numpy
                if (iou > 0.5f || j == imax) {
                    s[t] = NEGV;
                } else if (s[t] > lmax) {
                    lmax = s[t]; lidx = j;
                }
            }
        }
        // no extra barrier needed: rs/ri rewrite next iter is already fenced by this
        // iteration's __syncthreads() pair
    }
}

// ---------------- Kernel 2: per-image global top-300 + gather ----------------
#define OFF_B3D (NB * MAXDET * 4)                 // 9600
#define OFF_SC  (OFF_B3D + NB * MAXDET * 16)      // 48000
#define OFF_LAB (OFF_SC + NB * MAXDET)            // 50400

__global__ __launch_bounds__(256) void topk_kernel(
    const float4* __restrict__ boxes,
    const float*  __restrict__ b3d,
    const float*  __restrict__ sel_ws,
    const int*    __restrict__ idx_ws,
    float* __restrict__ out,
    int n)
{
    const int b = blockIdx.x;
    const int tid = threadIdx.x;
    const int M = NCLS * MAXDET;                  // 6000

    __shared__ float sv[NCLS * MAXDET];
    __shared__ int   selA[MAXDET];
    __shared__ int   selC[MAXDET];
    __shared__ float selS[MAXDET];
    __shared__ float rs[4];
    __shared__ int   ri[4];

    const float* sp = sel_ws + b * M;
    for (int f = tid; f < M; f += 256) sv[f] = sp[f];
    __syncthreads();

    for (int k = 0; k < MAXDET; ++k) {
        float lm = NEGV; int li = 0x7fffffff;
        for (int f = tid; f < M; f += 256) {
            float v = sv[f];
            if (v > lm || (v == lm && f < li)) { lm = v; li = f; }
        }
#pragma unroll
        for (int off = 32; off > 0; off >>= 1) {
            float ov = __shfl_xor(lm, off);
            int   oi = __shfl_xor(li, off);
            if (ov > lm || (ov == lm && oi < li)) { lm = ov; li = oi; }
        }
        if ((tid & 63) == 0) { rs[tid >> 6] = lm; ri[tid >> 6] = li; }
        __syncthreads();
        if (tid == 0) {
            float v2 = rs[0]; int i2 = ri[0];
#pragma unroll
            for (int w = 1; w < 4; ++w) {
                if (rs[w] > v2 || (rs[w] == v2 && ri[w] < i2)) { v2 = rs[w]; i2 = ri[w]; }
            }
            selS[k] = v2;
            selA[k] = idx_ws[b * M + i2];
            selC[k] = i2 / MAXDET;
            sv[i2] = NEGV;                        // remove without replacement
        }
        __syncthreads();
    }

    // gather + write outputs
    for (int k = tid; k < MAXDET; k += 256) {
        float sc = selS[k];
        int   a  = selA[k];
        int   c  = selC[k];
        bool ok = sc > NEGH;
        float4 bx = make_float4(-1.0f, -1.0f, -1.0f, -1.0f);
        if (ok) bx = boxes[(long)b * n + a];
        out[(long)b * MAXDET * 4 + k * 4 + 0] = bx.x;
        out[(long)b * MAXDET * 4 + k * 4 + 1] = bx.y;
        out[(long)b * MAXDET * 4 + k * 4 + 2] = bx.z;
        out[(long)b * MAXDET * 4 + k * 4 + 3] = bx.w;
        const float* bp = b3d + ((long)b * n + a) * 16;
        for (int q = 0; q < 16; ++q) {
            out[OFF_B3D + (long)b * MAXDET * 16 + k * 16 + q] = ok ? bp[q] : -1.0f;
        }
        out[OFF_SC  + (long)b * MAXDET + k] = ok ? sc : -1.0f;
        out[OFF_LAB + (long)b * MAXDET + k] = ok ? (float)c : -1.0f;
    }
}

extern "C" void kernel_launch(void* const* d_in, const int* in_sizes, int n_in,
                              void* d_out, int out_size, void* d_ws, size_t ws_size,
                              hipStream_t stream)
{
    const float* boxes = (const float*)d_in[0];   // [8, N, 4]
    const float* b3d   = (const float*)d_in[1];   // [8, N, 16]
    const float* cls   = (const float*)d_in[2];   // [8, N, 20]
    float* out = (float*)d_out;

    const int n = in_sizes[0] / (NB * 4);         // 49104

    float* sel_ws = (float*)d_ws;                               // 160*300 floats
    int*   idx_ws = (int*)((char*)d_ws + NB * NCLS * MAXDET * sizeof(float));

    hipLaunchKernelGGL(nms_pair_kernel, dim3(NB * NCLS), dim3(BLK), 0, stream,
                       (const float4*)boxes, cls, sel_ws, idx_ws, n);
    hipLaunchKernelGGL(topk_kernel, dim3(NB), dim3(256), 0, stream,
                       (const float4*)boxes, b3d, sel_ws, idx_ws, out, n);
}

// Round 2
// 10158.634 us; speedup vs baseline: 1.1150x; 1.1150x over previous
//
#include <hip/hip_runtime.h>

#define NCLS   20
#define NB     8
#define MAXDET 300
#define NEGV   (-1e9f)
#define NEGH   (-5e8f)   /* NEG/2 */
#define NPT    48
#define BLK    1024

typedef unsigned long long u64;
typedef unsigned int u32;

// ---------------- Kernel 1: per (b,c) greedy NMS, reference-exact ----------------
// blockIdx remap: b = blockIdx.x % 8 -> all 20 class-blocks of image b land on
// XCD b (round-robin dispatch), so the image's 786KB box array stays in that
// XCD's 4MB L2 across all 300 iterations.
__global__ __launch_bounds__(BLK, 2) void nms_pair_kernel(
    const float4* __restrict__ boxes,   // [B, N] of float4
    const float*  __restrict__ cls,     // [B, N, C]
    float* __restrict__ sel_ws,         // [B*C, MAXDET]
    int*   __restrict__ idx_ws,         // [B*C, MAXDET]
    int n)
{
    const int b = blockIdx.x & 7;            // XCD-aware: same image -> same XCD
    const int c = blockIdx.x >> 3;
    const int pair = b * NCLS + c;
    const int tid = threadIdx.x;

    const float4* bb = boxes + (long)b * n;
    const float*  cb = cls + (long)b * n * NCLS + c;

    float s[NPT];
    float lmax = NEGV; int lidx = 0x7fffffff;
#pragma unroll
    for (int t = 0; t < NPT; ++t) {
        int j = t * BLK + tid;
        float v = NEGV;
        if (j < n) {
            float sc = cb[(long)j * NCLS];
            if (sc > 0.05f) v = sc;          // strict >, like reference
        }
        s[t] = v;
        if (v > lmax) { lmax = v; lidx = j; }  // j ascending in t -> first occurrence kept
    }

    __shared__ u64 rk[16];
    __shared__ u64 bk_s;

    float* selp = sel_ws + pair * MAXDET;
    int*   idxp = idx_ws + pair * MAXDET;

    for (int k = 0; k < MAXDET; ++k) {
        // ---- packed-key block argmax (tie -> lowest index, matching jnp.argmax) ----
        // valid scores are > 0.05 (positive floats): bits^0x80000000 is order-preserving.
        u64 key = 0;
        if (lmax > NEGH) {
            key = ((u64)(__float_as_uint(lmax) ^ 0x80000000u) << 32) | (u32)(~lidx);
        }
#pragma unroll
        for (int off = 32; off > 0; off >>= 1) {
            u64 ok = __shfl_xor(key, off);
            if (ok > key) key = ok;
        }
        if ((tid & 63) == 0) rk[tid >> 6] = key;
        __syncthreads();
        if (tid < 64) {
            u64 k2 = (tid < 16) ? rk[tid] : 0ull;
#pragma unroll
            for (int off = 8; off > 0; off >>= 1) {
                u64 ok = __shfl_xor(k2, off);
                if (ok > k2) k2 = ok;
            }
            if (tid == 0) bk_s = k2;
        }
        __syncthreads();
        const u64 bkey = bk_s;

        if (bkey == 0) {
            // no valid candidates remain: every further iteration is invalid
            for (int f = k + tid; f < MAXDET; f += BLK) { selp[f] = NEGV; idxp[f] = 0; }
            break;
        }
        const int   imax = (int)~((u32)bkey);
        const float smax = __uint_as_float((u32)(bkey >> 32) ^ 0x80000000u);
        if (tid == 0) { selp[k] = smax; idxp[k] = imax; }

        const float4 bi4 = bb[imax];                       // broadcast load (L2-resident)
        const float area_i = (bi4.z - bi4.x) * (bi4.w - bi4.y);

        // ---- suppression pass fused with next-iteration local argmax ----
        lmax = NEGV; lidx = 0x7fffffff;
#pragma unroll
        for (int t = 0; t < NPT; ++t) {
            if (s[t] > NEGH) {
                int j = t * BLK + tid;
                float4 bj = bb[j];
                float ltx = fmaxf(bi4.x, bj.x);
                float lty = fmaxf(bi4.y, bj.y);
                float rbx = fminf(bi4.z, bj.z);
                float rby = fminf(bi4.w, bj.w);
                float wx = fmaxf(rbx - ltx, 0.0f);
                float wy = fmaxf(rby - lty, 0.0f);
                float inter = wx * wy;
                float area_j = (bj.z - bj.x) * (bj.w - bj.y);
                float den = area_j + area_i - inter + 1e-9f;  // ((aj+ai)-inter)+1e-9, ref order
                float iou = inter / den;                      // IEEE fp32 divide
                if (iou > 0.5f || j == imax) {
                    s[t] = NEGV;
                } else if (s[t] > lmax) {
                    lmax = s[t]; lidx = j;
                }
            }
        }
    }
}

// ---------------- Kernel 2: per-image global top-300 + gather ----------------
#define OFF_B3D (NB * MAXDET * 4)                 // 9600
#define OFF_SC  (OFF_B3D + NB * MAXDET * 16)      // 48000
#define OFF_LAB (OFF_SC + NB * MAXDET)            // 50400

__global__ __launch_bounds__(1024) void topk_kernel(
    const float4* __restrict__ boxes,
    const float*  __restrict__ b3d,
    const float*  __restrict__ sel_ws,
    const int*    __restrict__ idx_ws,
    float* __restrict__ out,
    int n)
{
    const int b = blockIdx.x;
    const int tid = threadIdx.x;
    const int M = NCLS * MAXDET;                  // 6000

    __shared__ float sv[NCLS * MAXDET];
    __shared__ int   selA[MAXDET];
    __shared__ int   selC[MAXDET];
    __shared__ float selS[MAXDET];
    __shared__ u64   rk[16];

    const float* sp = sel_ws + b * M;
    for (int f = tid; f < M; f += 1024) sv[f] = sp[f];
    __syncthreads();

    for (int k = 0; k < MAXDET; ++k) {
        // local scan: monotone-map score bits (NEG entries are all equal; tie -> lowest f)
        u64 key = 0;
        for (int f = tid; f < M; f += 1024) {
            u32 bits = __float_as_uint(sv[f]);
            u32 m = bits ^ (((int)bits < 0) ? 0xFFFFFFFFu : 0x80000000u);
            u64 cand = ((u64)m << 32) | (u32)(~f);
            if (cand > key) key = cand;
        }
#pragma unroll
        for (int off = 32; off > 0; off >>= 1) {
            u64 ok = __shfl_xor(key, off);
            if (ok > key) key = ok;
        }
        if ((tid & 63) == 0) rk[tid >> 6] = key;
        __syncthreads();
        if (tid == 0) {
            u64 k2 = rk[0];
#pragma unroll
            for (int w = 1; w < 16; ++w) if (rk[w] > k2) k2 = rk[w];
            int i2 = (int)~((u32)k2);
            u32 m = (u32)(k2 >> 32);
            u32 bits = ((int)(m) < 0) ? (m ^ 0x80000000u) : ~m;   // inverse monotone map
            selS[k] = __uint_as_float(bits);
            selA[k] = idx_ws[b * M + i2];
            selC[k] = i2 / MAXDET;
            sv[i2] = NEGV;                        // remove without replacement
        }
        __syncthreads();
    }

    // gather + write outputs
    for (int k = tid; k < MAXDET; k += 1024) {
        float sc = selS[k];
        int   a  = selA[k];
        int   c  = selC[k];
        bool ok = sc > NEGH;
        float4 bx = make_float4(-1.0f, -1.0f, -1.0f, -1.0f);
        if (ok) bx = boxes[(long)b * n + a];
        out[(long)b * MAXDET * 4 + k * 4 + 0] = bx.x;
        out[(long)b * MAXDET * 4 + k * 4 + 1] = bx.y;
        out[(long)b * MAXDET * 4 + k * 4 + 2] = bx.z;
        out[(long)b * MAXDET * 4 + k * 4 + 3] = bx.w;
        const float* bp = b3d + ((long)b * n + a) * 16;
        for (int q = 0; q < 16; ++q) {
            out[OFF_B3D + (long)b * MAXDET * 16 + k * 16 + q] = ok ? bp[q] : -1.0f;
        }
        out[OFF_SC  + (long)b * MAXDET + k] = ok ? sc : -1.0f;
        out[OFF_LAB + (long)b * MAXDET + k] = ok ? (float)c : -1.0f;
    }
}

extern "C" void kernel_launch(void* const* d_in, const int* in_sizes, int n_in,
                              void* d_out, int out_size, void* d_ws, size_t ws_size,
                              hipStream_t stream)
{
    const float* boxes = (const float*)d_in[0];   // [8, N, 4]
    const float* b3d   = (const float*)d_in[1];   // [8, N, 16]
    const float* cls   = (const float*)d_in[2];   // [8, N, 20]
    float* out = (float*)d_out;

    const int n = in_sizes[0] / (NB * 4);         // 49104

    float* sel_ws = (float*)d_ws;                               // 160*300 floats
    int*   idx_ws = (int*)((char*)d_ws + NB * NCLS * MAXDET * sizeof(float));

    hipLaunchKernelGGL(nms_pair_kernel, dim3(NB * NCLS), dim3(BLK), 0, stream,
                       (const float4*)boxes, cls, sel_ws, idx_ws, n);
    hipLaunchKernelGGL(topk_kernel, dim3(NB), dim3(1024), 0, stream,
                       (const float4*)boxes, b3d, sel_ws, idx_ws, out, n);
}

// Round 3
// 3431.399 us; speedup vs baseline: 3.3010x; 2.9605x over previous
//
#include <hip/hip_runtime.h>

#define NCLS   20
#define NB     8
#define MAXDET 300
#define NEGV   (-1e9f)
#define NEGH   (-5e8f)   /* NEG/2 */
#define NPT    48
#define BLK    1024
#define TBATCH 16
// RN(inter/den) > 0.5  <=>  fmaf(MC, den, -inter) < 0   (den>0; sign of fma exact)
#define MC     0x1.000002p-1f

typedef unsigned long long u64;
typedef unsigned int u32;

__device__ __forceinline__ u64 packkey(float s, int j) {
    // valid scores are > 0.05 (positive): bits^0x80000000 is order-preserving
    return ((u64)(__float_as_uint(s) ^ 0x80000000u) << 32) | (u32)(~(u32)j);
}
__device__ __forceinline__ u64 wredmax64(u64 k) {
#pragma unroll
    for (int off = 32; off > 0; off >>= 1) {
        u64 o = __shfl_xor(k, off);
        if (o > k) k = o;
    }
    return k;
}

// ---------------- Kernel 1: per (b,c) batched greedy NMS, reference-exact ----------------
__global__ __launch_bounds__(BLK, 1) void nms_pair_kernel(
    const float4* __restrict__ boxes,   // [B, N] of float4
    const float*  __restrict__ cls,     // [B, N, C]
    float* __restrict__ sel_ws,         // [B*C, MAXDET]
    int*   __restrict__ idx_ws,         // [B*C, MAXDET]
    int n)
{
    const int b = blockIdx.x & 7;            // XCD-aware: same image -> same XCD L2
    const int c = blockIdx.x >> 3;
    const int pair = b * NCLS + c;
    const int tid = threadIdx.x;
    const int lane = tid & 63;
    const int wv = tid >> 6;

    const float4* bb = boxes + (long)b * n;
    const float*  cb = cls + (long)b * n * NCLS + c;
    float* selp = sel_ws + pair * MAXDET;
    int*   idxp = idx_ws + pair * MAXDET;

    __shared__ u64   wl[16 * TBATCH];        // per-wave top-16 lists
    __shared__ float accb[TBATCH][5];        // accepted boxes (padded): x1,y1,x2,y2,area
    __shared__ int   sctrl[2];               // k_next, done

    float s[NPT];
    u64 m1 = 0, m2 = 0;                      // per-lane top-2 keys
#pragma unroll
    for (int t = 0; t < NPT; ++t) {
        int j = t * BLK + tid;
        float v = NEGV;
        if (j < n) {
            float sc = cb[(long)j * NCLS];
            if (sc > 0.05f) v = sc;          // strict >, like reference
        }
        s[t] = v;
        if (v > NEGH) {
            u64 kk = packkey(v, j);
            if (kk > m1) { m2 = m1; m1 = kk; } else if (kk > m2) m2 = kk;
        }
    }

    int k = 0;
    for (int iter = 0; iter < MAXDET + 1; ++iter) {
        // ---- Phase B: per-wave top-16 (sequential wave-argmax w/ top-2 backup) ----
        if (lane < TBATCH) wl[wv * TBATCH + lane] = 0;
        {
            u64 mm1 = m1, mm2 = m2, last = ~0ull;
            bool needrc = false;
            for (int w = 0; w < TBATCH; ++w) {
                if (needrc) {                // rare: lane popped twice, bounded recompute
                    u64 best = 0;
#pragma unroll
                    for (int t = 0; t < NPT; ++t) {
                        if (s[t] > NEGH) {
                            u64 kk = packkey(s[t], t * BLK + tid);
                            if (kk < last && kk > best) best = kk;
                        }
                    }
                    mm1 = best; needrc = false;
                }
                u64 r = wredmax64(mm1);
                if (r == 0) break;
                if (lane == w) wl[wv * TBATCH + w] = r;
                u64 bal = __ballot(mm1 == r);
                int wlx = __ffsll((long long)bal) - 1;
                if (lane == wlx) {
                    last = r;
                    if (mm2) { mm1 = mm2; mm2 = 0; }
                    else     { mm1 = 0; needrc = true; }
                }
            }
        }
        __syncthreads();

        // ---- Phase C: wave0 merges 256 keys -> global top-16, sims batch, records ----
        if (wv == 0) {
            u64 kk0 = wl[lane], kk1 = wl[lane + 64], kk2 = wl[lane + 128], kk3 = wl[lane + 192];
            u64 mykey = 0;
            int bcnt = 0;
            for (int m = 0; m < TBATCH; ++m) {
                u64 loc = kk0 > kk1 ? kk0 : kk1;
                u64 lc2 = kk2 > kk3 ? kk2 : kk3;
                if (lc2 > loc) loc = lc2;
                u64 r = wredmax64(loc);
                if (r == 0) break;
                u64 bal = __ballot(kk0 == r || kk1 == r || kk2 == r || kk3 == r);
                int wlx = __ffsll((long long)bal) - 1;
                if (lane == wlx) {
                    if (kk0 == r) kk0 = 0; else if (kk1 == r) kk1 = 0;
                    else if (kk2 == r) kk2 = 0; else kk3 = 0;
                }
                if (lane == m) mykey = r;
                bcnt = m + 1;
            }
            bool havekey = (lane < bcnt) && (mykey != 0);
            int myidx = havekey ? (int)(~(u32)mykey) : 0;
            float mysc = __uint_as_float((u32)(mykey >> 32) ^ 0x80000000u);
            float4 bx = bb[myidx];
            float myarea = (bx.z - bx.x) * (bx.w - bx.y);
            // intra-batch greedy sim: member m accepted iff no earlier ACCEPTED member kills it
            bool acc = false;
            for (int m = 0; m < bcnt; ++m) {
                float x1m = __shfl(bx.x, m), y1m = __shfl(bx.y, m);
                float x2m = __shfl(bx.z, m), y2m = __shfl(bx.w, m);
                float am  = __shfl(myarea, m);
                bool kill = false;
                if (acc && lane < m) {
                    float ltx = fmaxf(bx.x, x1m), lty = fmaxf(bx.y, y1m);
                    float rbx = fminf(bx.z, x2m), rby = fminf(bx.w, y2m);
                    float wx = fmaxf(rbx - ltx, 0.0f), wy = fmaxf(rby - lty, 0.0f);
                    float inter = wx * wy;
                    float den = ((am + myarea) - inter) + 1e-9f;   // (area_cand + area_sel) order = ref
                    kill = (fmaf(MC, den, -inter) < 0.0f);
                }
                u64 kb = __ballot(kill);
                if (lane == m) acc = (kb == 0);
            }
            u64 amask = __ballot(acc);
            int cnt  = __popcll(amask);
            int rank = __popcll(amask & ((1ull << lane) - 1));
            if (acc && rank < MAXDET - k) { selp[k + rank] = mysc; idxp[k + rank] = myidx; }
            // accepted boxes (ordered, padded with inert boxes) -> LDS
            if (lane < TBATCH) {
                accb[lane][0] = 1e30f; accb[lane][1] = 1e30f;
                accb[lane][2] = 1e30f; accb[lane][3] = 1e30f; accb[lane][4] = 0.0f;
            }
            if (acc) {                        // rank < 16 always; same-wave ds order is safe
                accb[rank][0] = bx.x; accb[rank][1] = bx.y;
                accb[rank][2] = bx.z; accb[rank][3] = bx.w; accb[rank][4] = myarea;
            }
            if (lane == 0) {
                int rec = cnt < (MAXDET - k) ? cnt : (MAXDET - k);
                sctrl[0] = k + rec;
                sctrl[1] = ((k + rec) >= MAXDET) || (bcnt < TBATCH);
            }
        }
        __syncthreads();
        k = sctrl[0];
        if (sctrl[1]) {                       // done: fill tail with NEG / idx 0 (ref argmax of all-NEG)
            for (int f = k + tid; f < MAXDET; f += BLK) { selp[f] = NEGV; idxp[f] = 0; }
            break;
        }

        // ---- Phase A: one suppression pass vs <=16 accepted (SGPR-held), rebuild top-2 ----
        float ax1[TBATCH], ay1[TBATCH], ax2[TBATCH], ay2[TBATCH], aar[TBATCH];
#pragma unroll
        for (int a = 0; a < TBATCH; ++a) {
            ax1[a] = __uint_as_float((u32)__builtin_amdgcn_readfirstlane((int)__float_as_uint(accb[a][0])));
            ay1[a] = __uint_as_float((u32)__builtin_amdgcn_readfirstlane((int)__float_as_uint(accb[a][1])));
            ax2[a] = __uint_as_float((u32)__builtin_amdgcn_readfirstlane((int)__float_as_uint(accb[a][2])));
            ay2[a] = __uint_as_float((u32)__builtin_amdgcn_readfirstlane((int)__float_as_uint(accb[a][3])));
            aar[a] = __uint_as_float((u32)__builtin_amdgcn_readfirstlane((int)__float_as_uint(accb[a][4])));
        }
        m1 = 0; m2 = 0;
#pragma unroll
        for (int t = 0; t < NPT; ++t) {
            int j = t * BLK + tid;
            int jc = j < n ? j : (n - 1);
            float4 bj = bb[jc];               // unconditional, coalesced, pipelined
            float st = s[t];
            if (st > NEGH) {
                float aj = (bj.z - bj.x) * (bj.w - bj.y);
                bool sup = false;
#pragma unroll
                for (int a = 0; a < TBATCH; ++a) {
                    float ltx = fmaxf(ax1[a], bj.x);
                    float lty = fmaxf(ay1[a], bj.y);
                    float rbx = fminf(ax2[a], bj.z);
                    float rby = fminf(ay2[a], bj.w);
                    float wx = fmaxf(rbx - ltx, 0.0f);
                    float wy = fmaxf(rby - lty, 0.0f);
                    float inter = wx * wy;
                    float den = ((aj + aar[a]) - inter) + 1e-9f;  // ref op order
                    sup = sup || (fmaf(MC, den, -inter) < 0.0f);
                }
                if (sup) s[t] = NEGV;
                else {
                    u64 kk = packkey(st, j);
                    if (kk > m1) { m2 = m1; m1 = kk; } else if (kk > m2) m2 = kk;
                }
            }
        }
    }
}

// ---------------- Kernel 2: per-image 20-way merge of sorted lists + gather ----------------
#define OFF_B3D (NB * MAXDET * 4)                 // 9600
#define OFF_SC  (OFF_B3D + NB * MAXDET * 16)      // 48000
#define OFF_LAB (OFF_SC + NB * MAXDET)            // 50400

__global__ __launch_bounds__(256, 1) void topk_kernel(
    const float4* __restrict__ boxes,
    const float*  __restrict__ b3d,
    const float*  __restrict__ sel_ws,
    const int*    __restrict__ idx_ws,
    float* __restrict__ out,
    int n)
{
    const int b = blockIdx.x;
    const int tid = threadIdx.x;
    const int lane = tid & 63;
    const int M = NCLS * MAXDET;                  // 6000

    __shared__ float sv[NCLS * MAXDET];
    __shared__ int   mF[MAXDET];
    __shared__ float mS[MAXDET];

    const float* sp = sel_ws + b * M;
    for (int f = tid; f < M; f += 256) sv[f] = sp[f];
    __syncthreads();

    if (tid < 64) {
        // per-class NMS output is descending (ties: index asc) == top_k order -> 20-way merge
        int pos = 0;
        for (int k = 0; k < MAXDET; ++k) {
            u64 key = 0;
            if (lane < NCLS && pos < MAXDET) {
                float v = sv[lane * MAXDET + pos];
                u32 bits = __float_as_uint(v);
                u32 m = bits ^ (((int)bits < 0) ? 0xFFFFFFFFu : 0x80000000u);
                key = ((u64)m << 32) | (u32)(~(u32)(lane * MAXDET + pos));
            }
            u64 r = wredmax64(key);
            u64 bal = __ballot(key == r && key != 0);
            int wlx = __ffsll((long long)bal) - 1;
            if (lane == wlx) pos++;
            if (lane == 0) {
                u32 mm = (u32)(r >> 32);
                u32 bits = (mm & 0x80000000u) ? (mm ^ 0x80000000u) : ~mm;
                mF[k] = (int)(~(u32)r);
                mS[k] = __uint_as_float(bits);
            }
        }
    }
    __syncthreads();

    for (int k = tid; k < MAXDET; k += 256) {
        float sc = mS[k];
        int flat = mF[k];
        int a = idx_ws[b * M + flat];
        int c = flat / MAXDET;
        bool ok = sc > NEGH;
        float4 bx = make_float4(-1.0f, -1.0f, -1.0f, -1.0f);
        if (ok) bx = boxes[(long)b * n + a];
        out[(long)b * MAXDET * 4 + k * 4 + 0] = bx.x;
        out[(long)b * MAXDET * 4 + k * 4 + 1] = bx.y;
        out[(long)b * MAXDET * 4 + k * 4 + 2] = bx.z;
        out[(long)b * MAXDET * 4 + k * 4 + 3] = bx.w;
        const float* bp = b3d + ((long)b * n + a) * 16;
        for (int q = 0; q < 16; ++q) {
            out[OFF_B3D + (long)b * MAXDET * 16 + k * 16 + q] = ok ? bp[q] : -1.0f;
        }
        out[OFF_SC  + (long)b * MAXDET + k] = ok ? sc : -1.0f;
        out[OFF_LAB + (long)b * MAXDET + k] = ok ? (float)c : -1.0f;
    }
}

extern "C" void kernel_launch(void* const* d_in, const int* in_sizes, int n_in,
                              void* d_out, int out_size, void* d_ws, size_t ws_size,
                              hipStream_t stream)
{
    const float* boxes = (const float*)d_in[0];   // [8, N, 4]
    const float* b3d   = (const float*)d_in[1];   // [8, N, 16]
    const float* cls   = (const float*)d_in[2];   // [8, N, 20]
    float* out = (float*)d_out;

    const int n = in_sizes[0] / (NB * 4);         // 49104

    float* sel_ws = (float*)d_ws;                 // 160*300 floats
    int*   idx_ws = (int*)((char*)d_ws + NB * NCLS * MAXDET * sizeof(float));

    hipLaunchKernelGGL(nms_pair_kernel, dim3(NB * NCLS), dim3(BLK), 0, stream,
                       (const float4*)boxes, cls, sel_ws, idx_ws, n);
    hipLaunchKernelGGL(topk_kernel, dim3(NB), dim3(256), 0, stream,
                       (const float4*)boxes, b3d, sel_ws, idx_ws, out, n);
}

// Round 4
// 271.587 us; speedup vs baseline: 41.7065x; 12.6346x over previous
//
#include <hip/hip_runtime.h>

#define NCLS    20
#define NB      8
#define MAXDET  300
#define NEGV    (-1e9f)
#define NEGH    (-5e8f)   /* NEG/2 */
#define BLK     1024
#define KTARGET 512
#define KMAX    1024
#define NBINS   4096

typedef unsigned long long u64;
typedef unsigned int u32;

__device__ __forceinline__ u64 packkey(float s, int j) {
    // valid scores are > 0.05 (positive): bits^0x80000000 is order-preserving;
    // ~j breaks ties toward smaller index (larger key = earlier in greedy order)
    return ((u64)(__float_as_uint(s) ^ 0x80000000u) << 32) | (u32)(~(u32)j);
}
__device__ __forceinline__ u64 wredmax64(u64 k) {
#pragma unroll
    for (int off = 32; off > 0; off >>= 1) {
        u64 o = __shfl_xor(k, off);
        if (o > k) k = o;
    }
    return k;
}

// ---------------- Kernel 0: transpose cls [B,N,C] -> clsT [B*C, N] ----------------
__global__ __launch_bounds__(256) void transpose_cls_kernel(
    const float* __restrict__ cls, float* __restrict__ clsT, int n)
{
    __shared__ float t[256][NCLS + 1];
    const int b = blockIdx.y;
    const int n0 = blockIdx.x * 256;
    const int tid = threadIdx.x;
    const float* src = cls + (long)b * n * NCLS;
    for (int i = tid; i < 256 * NCLS; i += 256) {
        int r = i / NCLS, cc = i - r * NCLS;
        if (n0 + r < n) t[r][cc] = src[(long)n0 * NCLS + i];
    }
    __syncthreads();
    int gr = n0 + tid;
    if (gr < n) {
        for (int cc = 0; cc < NCLS; ++cc)
            clsT[((long)b * NCLS + cc) * n + gr] = t[tid][cc];
    }
}

// ---------------- Kernel 1: per (b,c) top-K prefix greedy NMS, reference-exact ----------------
template<bool TP>
__global__ __launch_bounds__(BLK, 1) void nms_kernel(
    const float4* __restrict__ boxes,   // [B, N] of float4
    const float*  __restrict__ cls,     // [B, N, C] (strided fallback)
    const float*  __restrict__ clsT,    // [B*C, N]  (transposed path)
    float* __restrict__ sel_ws,         // [B*C, MAXDET]
    int*   __restrict__ idx_ws,         // [B*C, MAXDET]
    int n)
{
    const int b = blockIdx.x & 7;            // XCD-aware: same image -> same XCD L2
    const int c = blockIdx.x >> 3;
    const int pair = b * NCLS + c;
    const int tid = threadIdx.x;
    const int lane = tid & 63;
    const int wv = tid >> 6;

    const float4* bb = boxes + (long)b * n;
    const float* srow = TP ? (clsT + (long)pair * n) : (cls + (long)b * n * NCLS + c);
    float* selp = sel_ws + pair * MAXDET;
    int*   idxp = idx_ws + pair * MAXDET;

    __shared__ u32  hist[NBINS];                       // 16KB
    __shared__ u64  keys[KMAX];                        // 8KB
    __shared__ float aX1[MAXDET], aY1[MAXDET], aX2[MAXDET], aY2[MAXDET], aAr[MAXDET];
    __shared__ int  wts[16];
    __shared__ int  ews[16];
    __shared__ u64  wl[16];
    __shared__ int  ctrl[8];   // 0:B 1:cumAbove 2:cumTotal 3:cntLo 4:cntHi 5:k 6:remaining
    __shared__ u32  supm[2];
    __shared__ u64  ubk;

    auto sc_at = [&](int j) -> float { return TP ? srow[j] : srow[(long)j * NCLS]; };

    if (tid == 0) { ubk = ~0ull; ctrl[5] = 0; }
    __syncthreads();

    while (true) {
        const u64 UB = ubk;                            // uniform (read after barrier)
        // ---- zero hist / keys / counters ----
        for (int i = tid; i < NBINS; i += BLK) hist[i] = 0;
        keys[tid] = 0;
        if (tid == 0) { ctrl[0] = 0; ctrl[3] = 0; ctrl[4] = 0; }
        __syncthreads();

        // ---- pass 1: histogram of valid keys < UB ----
        for (int j = tid; j < n; j += BLK) {
            float sc = sc_at(j);
            if (sc > 0.05f) {                          // strict >, like reference
                u64 ky = packkey(sc, j);
                if (ky < UB) {
                    int bkt = (int)(sc * 4096.0f); if (bkt > 4095) bkt = 4095;
                    atomicAdd(&hist[bkt], 1u);
                }
            }
        }
        __syncthreads();

        // ---- block suffix-scan over 4096 bins, find boundary bin B ----
        int h0 = hist[4 * tid], h1 = hist[4 * tid + 1], h2 = hist[4 * tid + 2], h3 = hist[4 * tid + 3];
        int acc = h0 + h1 + h2 + h3;
#pragma unroll
        for (int d = 1; d < 64; d <<= 1) {
            int o = __shfl_down(acc, d);
            if (lane + d < 64) acc += o;               // within-wave inclusive suffix sum
        }
        if (lane == 0) wts[wv] = acc;
        __syncthreads();
        if (tid < 16) { int e = 0; for (int w = tid + 1; w < 16; ++w) e += wts[w]; ews[tid] = e; }
        __syncthreads();
        const int Ti = acc + ews[wv];                  // suffix sum from this thread's bins
        const int S0 = Ti, S1 = Ti - h0, S2 = S1 - h1, S3 = S2 - h2;
        int bestb = -1;
        if      (S3 >= KTARGET) bestb = 4 * tid + 3;
        else if (S2 >= KTARGET) bestb = 4 * tid + 2;
        else if (S1 >= KTARGET) bestb = 4 * tid + 1;
        else if (S0 >= KTARGET) bestb = 4 * tid;
        if (bestb >= 0) atomicMax(&ctrl[0], bestb);
        if (tid == 0) ctrl[2] = Ti;                    // cumTotal (thread 0 suffix = all)
        __syncthreads();
        const int B = ctrl[0];
        if ((B >> 2) == tid) {
            int q = B & 3;
            int SB = (q == 0) ? S0 : (q == 1) ? S1 : (q == 2) ? S2 : S3;
            int hq = (q == 0) ? h0 : (q == 1) ? h1 : (q == 2) ? h2 : h3;
            ctrl[1] = SB - hq;                         // cumAbove = S(B+1) < KTARGET
        }
        __syncthreads();
        const int cumTotal = ctrl[2];
        if (cumTotal == 0) break;                      // nothing left at all
        const int cumAbove = ctrl[1];

        // ---- pass 2: collect (hi class guaranteed, boundary class capped) ----
        for (int j = tid; j < n; j += BLK) {
            float sc = sc_at(j);
            if (sc > 0.05f) {
                u64 ky = packkey(sc, j);
                if (ky < UB) {
                    int bkt = (int)(sc * 4096.0f); if (bkt > 4095) bkt = 4095;
                    if (bkt > B) {
                        int slot = atomicAdd(&ctrl[4], 1);   // < cumAbove < KMAX guaranteed
                        keys[slot] = ky;
                    } else if (bkt == B) {
                        int p = atomicAdd(&ctrl[3], 1);
                        int pos = KMAX - 1 - p;
                        if (pos >= cumAbove) keys[pos] = ky; // else dropped (untrusted region)
                    }
                }
            }
        }
        __syncthreads();
        const int cntLo = ctrl[3];
        const int Mreal = cumAbove + cntLo;
        const bool dropped = Mreal > KMAX;
        int trusted = dropped ? cumAbove : Mreal;

        if (trusted > 0) {
            // ---- bitonic sort desc over KMAX (zeros sink to bottom) ----
            for (int k2 = 2; k2 <= KMAX; k2 <<= 1) {
                for (int jj = k2 >> 1; jj > 0; jj >>= 1) {
                    int ixj = tid ^ jj;
                    if (ixj > tid) {
                        u64 a = keys[tid], v = keys[ixj];
                        bool desc = ((tid & k2) == 0);
                        bool sw = desc ? (a < v) : (a > v);
                        if (sw) { keys[tid] = v; keys[ixj] = a; }
                    }
                    __syncthreads();
                }
            }
        } else {
            // rare fallback: single best candidate < UB (guaranteed progress)
            u64 lb = 0;
            for (int j = tid; j < n; j += BLK) {
                float sc = sc_at(j);
                if (sc > 0.05f) { u64 ky = packkey(sc, j); if (ky < UB && ky > lb) lb = ky; }
            }
            lb = wredmax64(lb);
            if (lane == 0) wl[wv] = lb;
            __syncthreads();
            if (tid == 0) {
                u64 bk = 0;
                for (int w = 0; w < 16; ++w) if (wl[w] > bk) bk = wl[w];
                keys[0] = bk;
            }
            trusted = 1;
            __syncthreads();
        }

        // ---- greedy over sorted prefix, 64-wide chunks ----
        if (tid == 0) { supm[0] = 0; supm[1] = 0; }
        __syncthreads();
        for (int base = 0; base < trusted; base += 64) {
            const int kcur = ctrl[5];                  // uniform after barrier
            if (kcur >= MAXDET) break;
            int ci = base + lane;
            bool have = ci < trusted;
            u64 ky = have ? keys[ci] : 0;
            int idx = have ? (int)(~(u32)ky) : 0;
            float4 bx = bb[idx];
            float ar = (bx.z - bx.x) * (bx.w - bx.y);
            // check vs prior accepted, split across 16 waves
            bool sup = false;
            for (int a = wv; a < kcur; a += 16) {
                float ltx = fmaxf(aX1[a], bx.x), lty = fmaxf(aY1[a], bx.y);
                float rbx = fminf(aX2[a], bx.z), rby = fminf(aY2[a], bx.w);
                float wx = fmaxf(rbx - ltx, 0.0f), wy = fmaxf(rby - lty, 0.0f);
                float inter = wx * wy;
                float den = ((ar + aAr[a]) - inter) + 1e-9f;  // ref op order
                float iou = inter / den;                      // IEEE fp32 divide
                sup = sup || (iou > 0.5f);
            }
            u64 wsup = __ballot(sup && have);
            if (lane == 0 && wsup) { atomicOr(&supm[0], (u32)wsup); atomicOr(&supm[1], (u32)(wsup >> 32)); }
            __syncthreads();
            if (wv == 0) {
                // in-chunk sequential greedy sim on wave 0
                u64 smk = ((u64)supm[1] << 32) | (u64)supm[0];
                bool s2 = (smk >> lane) & 1;
                int kc2 = kcur;
                for (int m = 0; m < 64; ++m) {
                    u64 bal = __ballot(lane == m && have && !s2 && kc2 < MAXDET);
                    if (bal) {
                        float x1 = __shfl(bx.x, m), y1 = __shfl(bx.y, m);
                        float x2 = __shfl(bx.z, m), y2 = __shfl(bx.w, m);
                        float am = __shfl(ar, m);
                        if (lane > m) {
                            float ltx = fmaxf(x1, bx.x), lty = fmaxf(y1, bx.y);
                            float rbx = fminf(x2, bx.z), rby = fminf(y2, bx.w);
                            float wx = fmaxf(rbx - ltx, 0.0f), wy = fmaxf(rby - lty, 0.0f);
                            float inter = wx * wy;
                            float den = ((ar + am) - inter) + 1e-9f;
                            float iou = inter / den;
                            if (iou > 0.5f) s2 = true;
                        }
                        if (lane == m) {
                            aX1[kc2] = bx.x; aY1[kc2] = bx.y; aX2[kc2] = bx.z; aY2[kc2] = bx.w; aAr[kc2] = ar;
                            selp[kc2] = __uint_as_float((u32)(ky >> 32) ^ 0x80000000u);
                            idxp[kc2] = idx;
                        }
                        kc2++;
                    }
                }
                if (lane == 0) { ctrl[5] = kc2; supm[0] = 0; supm[1] = 0; }
            }
            __syncthreads();
        }

        // ---- update UB / remaining ----
        if (tid == 0) {
            ubk = keys[trusted - 1];
            ctrl[6] = cumTotal - trusted;
        }
        __syncthreads();
        if (ctrl[5] >= MAXDET || ctrl[6] <= 0) break;
    }

    const int kfin = ctrl[5];
    for (int f = kfin + tid; f < MAXDET; f += BLK) { selp[f] = NEGV; idxp[f] = 0; }
}

// ---------------- Kernel 2: per-image 20-way merge of sorted lists + gather ----------------
#define OFF_B3D (NB * MAXDET * 4)                 // 9600
#define OFF_SC  (OFF_B3D + NB * MAXDET * 16)      // 48000
#define OFF_LAB (OFF_SC + NB * MAXDET)            // 50400

__global__ __launch_bounds__(256, 1) void topk_kernel(
    const float4* __restrict__ boxes,
    const float*  __restrict__ b3d,
    const float*  __restrict__ sel_ws,
    const int*    __restrict__ idx_ws,
    float* __restrict__ out,
    int n)
{
    const int b = blockIdx.x;
    const int tid = threadIdx.x;
    const int lane = tid & 63;
    const int M = NCLS * MAXDET;                  // 6000

    __shared__ float sv[NCLS * MAXDET];
    __shared__ int   mF[MAXDET];
    __shared__ float mS[MAXDET];

    const float* sp = sel_ws + b * M;
    for (int f = tid; f < M; f += 256) sv[f] = sp[f];
    __syncthreads();

    if (tid < 64) {
        // per-class NMS output is descending (ties: index asc) == top_k order -> 20-way merge
        int pos = 0;
        for (int k = 0; k < MAXDET; ++k) {
            u64 key = 0;
            if (lane < NCLS && pos < MAXDET) {
                float v = sv[lane * MAXDET + pos];
                u32 bits = __float_as_uint(v);
                u32 m = bits ^ (((int)bits < 0) ? 0xFFFFFFFFu : 0x80000000u);
                key = ((u64)m << 32) | (u32)(~(u32)(lane * MAXDET + pos));
            }
            u64 r = wredmax64(key);
            u64 bal = __ballot(key == r && key != 0);
            int wlx = __ffsll((long long)bal) - 1;
            if (lane == wlx) pos++;
            if (lane == 0) {
                u32 mm = (u32)(r >> 32);
                u32 bits = (mm & 0x80000000u) ? (mm ^ 0x80000000u) : ~mm;
                mF[k] = (int)(~(u32)r);
                mS[k] = __uint_as_float(bits);
            }
        }
    }
    __syncthreads();

    for (int k = tid; k < MAXDET; k += 256) {
        float sc = mS[k];
        int flat = mF[k];
        int a = idx_ws[b * M + flat];
        int c = flat / MAXDET;
        bool ok = sc > NEGH;
        float4 bx = make_float4(-1.0f, -1.0f, -1.0f, -1.0f);
        if (ok) bx = boxes[(long)b * n + a];
        out[(long)b * MAXDET * 4 + k * 4 + 0] = bx.x;
        out[(long)b * MAXDET * 4 + k * 4 + 1] = bx.y;
        out[(long)b * MAXDET * 4 + k * 4 + 2] = bx.z;
        out[(long)b * MAXDET * 4 + k * 4 + 3] = bx.w;
        const float* bp = b3d + ((long)b * n + a) * 16;
        for (int q = 0; q < 16; ++q) {
            out[OFF_B3D + (long)b * MAXDET * 16 + k * 16 + q] = ok ? bp[q] : -1.0f;
        }
        out[OFF_SC  + (long)b * MAXDET + k] = ok ? sc : -1.0f;
        out[OFF_LAB + (long)b * MAXDET + k] = ok ? (float)c : -1.0f;
    }
}

extern "C" void kernel_launch(void* const* d_in, const int* in_sizes, int n_in,
                              void* d_out, int out_size, void* d_ws, size_t ws_size,
                              hipStream_t stream)
{
    const float* boxes = (const float*)d_in[0];   // [8, N, 4]
    const float* b3d   = (const float*)d_in[1];   // [8, N, 16]
    const float* cls   = (const float*)d_in[2];   // [8, N, 20]
    float* out = (float*)d_out;

    const int n = in_sizes[0] / (NB * 4);         // 49104

    const size_t needT = (size_t)NB * NCLS * n * sizeof(float);     // ~31.4MB
    const size_t selB  = (size_t)NB * NCLS * MAXDET * sizeof(float);

    if (ws_size >= needT + 2 * selB) {
        float* clsT   = (float*)d_ws;
        float* sel_ws = (float*)((char*)d_ws + needT);
        int*   idx_ws = (int*)((char*)d_ws + needT + selB);
        hipLaunchKernelGGL(transpose_cls_kernel, dim3((n + 255) / 256, NB), dim3(256), 0, stream,
                           cls, clsT, n);
        hipLaunchKernelGGL((nms_kernel<true>), dim3(NB * NCLS), dim3(BLK), 0, stream,
                           (const float4*)boxes, cls, clsT, sel_ws, idx_ws, n);
        hipLaunchKernelGGL(topk_kernel, dim3(NB), dim3(256), 0, stream,
                           (const float4*)boxes, b3d, sel_ws, idx_ws, out, n);
    } else {
        float* sel_ws = (float*)d_ws;
        int*   idx_ws = (int*)((char*)d_ws + selB);
        hipLaunchKernelGGL((nms_kernel<false>), dim3(NB * NCLS), dim3(BLK), 0, stream,
                           (const float4*)boxes, cls, nullptr, sel_ws, idx_ws, n);
        hipLaunchKernelGGL(topk_kernel, dim3(NB), dim3(256), 0, stream,
                           (const float4*)boxes, b3d, sel_ws, idx_ws, out, n);
    }
}

// Round 5
// 116.820 us; speedup vs baseline: 96.9605x; 2.3248x over previous
//
#include <hip/hip_runtime.h>

#define NCLS    20
#define NB      8
#define MAXDET  300
#define NEGV    (-1e9f)
#define NEGH    (-5e8f)
#define BLKN    512
#define KTARGET 896
#define KMAX    1024

typedef unsigned long long u64;
typedef unsigned int u32;

__device__ __forceinline__ u64 packkey(float s, int j) {
    // valid scores are > 0.05 (positive): bits^0x80000000 order-preserving; ~j -> lower idx wins
    return ((u64)(__float_as_uint(s) ^ 0x80000000u) << 32) | (u32)(~(u32)j);
}
__device__ __forceinline__ u64 wredmax64(u64 k) {
#pragma unroll
    for (int off = 32; off > 0; off >>= 1) {
        u64 o = __shfl_xor(k, off);
        if (o > k) k = o;
    }
    return k;
}
__device__ __forceinline__ int binfull(float s) {
    int full = (int)(s * 262144.0f);          // 2^18 sub-resolution; monotone, self-consistent
    return full > 262143 ? 262143 : full;
}

// ---------------- Kernel 0: transpose cls [B,N,C] -> clsT [B*C, N] ----------------
__global__ __launch_bounds__(256) void transpose_cls_kernel(
    const float* __restrict__ cls, float* __restrict__ clsT, int n)
{
    __shared__ float t[256][NCLS + 1];
    const int b = blockIdx.y;
    const int n0 = blockIdx.x * 256;
    const int tid = threadIdx.x;
    const float* src = cls + (long)b * n * NCLS;
    for (int i = tid; i < 256 * NCLS; i += 256) {
        int r = i / NCLS, cc = i - r * NCLS;
        if (n0 + r < n) t[r][cc] = src[(long)n0 * NCLS + i];
    }
    __syncthreads();
    int gr = n0 + tid;
    if (gr < n) {
        for (int cc = 0; cc < NCLS; ++cc)
            clsT[((long)b * NCLS + cc) * n + gr] = t[tid][cc];
    }
}

// ---------------- Kernel 1: per (b,c) top-K prefix greedy NMS, reference-exact ----------------
template<bool TP>
__global__ __launch_bounds__(BLKN, 1) void nms_kernel(
    const float4* __restrict__ boxes,
    const float*  __restrict__ cls,
    const float*  __restrict__ clsT,
    float* __restrict__ sel_ws,
    int*   __restrict__ idx_ws,
    int n)
{
    const int b = blockIdx.x & 7;            // XCD-aware: same image -> same XCD L2
    const int c = blockIdx.x >> 3;
    const int pair = b * NCLS + c;
    const int tid = threadIdx.x;
    const int lane = tid & 63;
    const int wv = tid >> 6;                 // 0..7

    const float4* bb = boxes + (long)b * n;
    const float* srow = TP ? (clsT + (long)pair * n) : (cls + (long)b * n * NCLS + c);
    float* selp = sel_ws + pair * MAXDET;
    int*   idxp = idx_ws + pair * MAXDET;

    __shared__ u32   hist[BLKN];
    __shared__ u64   keys[KMAX];
    __shared__ float aX1[MAXDET], aY1[MAXDET], aX2[MAXDET], aY2[MAXDET], aAr[MAXDET];
    __shared__ float cx1[64], cy1[64], cx2[64], cy2[64], car[64];
    __shared__ u32   kb0[64], kb1[64], psupm[2];
    __shared__ int   wts[8], ews[8];
    __shared__ u64   wl[8];
    __shared__ int   ctrl[8];   // 0:B 1:cumAbove 2:cumTotal 3:cntLo 4:cntHi 5:k
    __shared__ u64   ubk;

    if (tid == 0) { ubk = ~0ull; ctrl[5] = 0; }
    __syncthreads();

    while (true) {
        const u64 UB = ubk;                  // uniform (read after barrier)
        hist[tid] = 0;
        keys[tid] = 0; keys[tid + BLKN] = 0;
        if (tid > 0 && tid < 5) ctrl[tid] = 0;
        if (tid == 0) ctrl[0] = -1;
        __syncthreads();

        // ---- pass 1: histogram of valid keys < UB ----
        if (TP) {
            const float4* s4 = (const float4*)srow;
            const int n4 = n >> 2;
            for (int q = tid; q < n4; q += BLKN) {
                float4 v = s4[q];
                const int j0 = q << 2;
                float ss[4] = {v.x, v.y, v.z, v.w};
#pragma unroll
                for (int e = 0; e < 4; ++e) {
                    float sc = ss[e];
                    if (sc > 0.05f) {
                        u64 ky = packkey(sc, j0 + e);
                        if (ky < UB) atomicAdd(&hist[binfull(sc) >> 9], 1u);
                    }
                }
            }
            for (int j = (n & ~3) + tid; j < n; j += BLKN) {
                float sc = srow[j];
                if (sc > 0.05f) { u64 ky = packkey(sc, j); if (ky < UB) atomicAdd(&hist[binfull(sc) >> 9], 1u); }
            }
        } else {
            for (int j = tid; j < n; j += BLKN) {
                float sc = srow[(long)j * NCLS];
                if (sc > 0.05f) { u64 ky = packkey(sc, j); if (ky < UB) atomicAdd(&hist[binfull(sc) >> 9], 1u); }
            }
        }
        __syncthreads();

        // ---- suffix scan over 512 bins (1 bin/thread) ----
        const int h = (int)hist[tid];
        int acc = h;
#pragma unroll
        for (int d = 1; d < 64; d <<= 1) {
            int o = __shfl_down(acc, d);
            if (lane + d < 64) acc += o;
        }
        if (lane == 0) wts[wv] = acc;
        __syncthreads();
        if (tid < 8) { int e = 0; for (int w = tid + 1; w < 8; ++w) e += wts[w]; ews[tid] = e; }
        __syncthreads();
        const int S = acc + ews[wv];         // suffix sum from bin tid
        if (S >= KTARGET && (S - h) < KTARGET) { ctrl[0] = tid; ctrl[1] = S - h; }  // unique crossing
        if (tid == 0) ctrl[2] = S;           // total
        __syncthreads();
        const int cumTotal = ctrl[2];
        if (cumTotal == 0) break;
        const int B = ctrl[0];               // -1 if total < KTARGET -> collect all
        const int cumAbove = ctrl[1];

        // ---- pass 2: collect (hi bins guaranteed, boundary bin capped) ----
#define COLLECT_BODY(SC, J) do { float sc_ = (SC); \
        if (sc_ > 0.05f) { u64 ky_ = packkey(sc_, (J)); if (ky_ < UB) { \
            int bkt_ = binfull(sc_) >> 9; \
            if (bkt_ > B) { int sl_ = atomicAdd(&ctrl[4], 1); if (sl_ < KMAX) keys[sl_] = ky_; } \
            else if (bkt_ == B) { int pp_ = atomicAdd(&ctrl[3], 1); int pos_ = KMAX - 1 - pp_; \
                if (pos_ >= cumAbove) keys[pos_] = ky_; } \
        } } } while (0)

        if (TP) {
            const float4* s4 = (const float4*)srow;
            const int n4 = n >> 2;
            for (int q = tid; q < n4; q += BLKN) {
                float4 v = s4[q];
                const int j0 = q << 2;
                COLLECT_BODY(v.x, j0); COLLECT_BODY(v.y, j0 + 1);
                COLLECT_BODY(v.z, j0 + 2); COLLECT_BODY(v.w, j0 + 3);
            }
            for (int j = (n & ~3) + tid; j < n; j += BLKN) COLLECT_BODY(srow[j], j);
        } else {
            for (int j = tid; j < n; j += BLKN) COLLECT_BODY(srow[(long)j * NCLS], j);
        }
#undef COLLECT_BODY
        __syncthreads();
        const int cntLo = ctrl[3];
        const int cntHi = ctrl[4];
        const int Mreal = cntHi + cntLo;
        int trusted = (Mreal > KMAX) ? cntHi : Mreal;

        if (trusted > 0) {
            // ---- bitonic sort desc over KMAX=1024 (512 comparators = 512 threads) ----
            for (int k2 = 2; k2 <= KMAX; k2 <<= 1) {
                for (int jj = k2 >> 1; jj > 0; jj >>= 1) {
                    const int i = ((tid & ~(jj - 1)) << 1) | (tid & (jj - 1));
                    const int ix = i | jj;
                    u64 a = keys[i], v = keys[ix];
                    const bool desc = ((i & k2) == 0);
                    if ((a < v) == desc) { keys[i] = v; keys[ix] = a; }
                    __syncthreads();
                }
            }
        } else {
            // rare: boundary-bin overflow with empty hi region -> single best key (progress)
            u64 lb = 0;
            if (TP) { for (int j = tid; j < n; j += BLKN) { float sc = srow[j];
                        if (sc > 0.05f) { u64 ky = packkey(sc, j); if (ky < UB && ky > lb) lb = ky; } } }
            else    { for (int j = tid; j < n; j += BLKN) { float sc = srow[(long)j * NCLS];
                        if (sc > 0.05f) { u64 ky = packkey(sc, j); if (ky < UB && ky > lb) lb = ky; } } }
            lb = wredmax64(lb);
            if (lane == 0) wl[wv] = lb;
            __syncthreads();
            if (tid == 0) { u64 bk = 0; for (int w = 0; w < 8; ++w) if (wl[w] > bk) bk = wl[w]; keys[0] = bk; }
            trusted = 1;
            __syncthreads();
        }

        // ---- greedy over sorted prefix: parallel kill-matrix + ballot fixpoint ----
        for (int base = 0; base < trusted; base += 64) {
            const int kcur = ctrl[5];        // uniform (after barrier)
            if (kcur >= MAXDET) break;
            if (tid < 64) {
                const int ci = base + tid;
                const bool have = ci < trusted;
                u64 ky = have ? keys[ci] : 0;
                float4 bx = make_float4(0.f, 0.f, 0.f, 0.f);   // inert for !have
                if (have) bx = bb[(int)(~(u32)ky)];
                cx1[tid] = bx.x; cy1[tid] = bx.y; cx2[tid] = bx.z; cy2[tid] = bx.w;
                car[tid] = (bx.z - bx.x) * (bx.w - bx.y);
                kb0[tid] = 0; kb1[tid] = 0;
            } else if (tid < 66) {
                psupm[tid - 64] = 0;
            }
            __syncthreads();

            const float px1 = cx1[lane], py1 = cy1[lane], px2 = cx2[lane], py2 = cy2[lane], par = car[lane];
            // (a) check candidate lane vs prior accepted, split across 8 waves
            bool sup = false;
            for (int a = wv; a < kcur; a += 8) {
                float ltx = fmaxf(aX1[a], px1), lty = fmaxf(aY1[a], py1);
                float rbx = fminf(aX2[a], px2), rby = fminf(aY2[a], py2);
                float wx = fmaxf(rbx - ltx, 0.0f), wy = fmaxf(rby - lty, 0.0f);
                float inter = wx * wy;
                float den = ((par + aAr[a]) - inter) + 1e-9f;   // ref op order
                sup = sup || (inter / den > 0.5f);              // IEEE divide
            }
            u64 bal = __ballot(sup);
            if (lane == 0 && bal) { atomicOr(&psupm[0], (u32)bal); atomicOr(&psupm[1], (u32)(bal >> 32)); }
            // (b) in-chunk kill matrix: killer j=lane, victim m (j<m), all pairs in parallel
#pragma unroll
            for (int r = 0; r < 8; ++r) {
                const int m = (r << 3) | wv;
                if (lane < m) {
                    float ltx = fmaxf(px1, cx1[m]), lty = fmaxf(py1, cy1[m]);
                    float rbx = fminf(px2, cx2[m]), rby = fminf(py2, cy2[m]);
                    float wx = fmaxf(rbx - ltx, 0.0f), wy = fmaxf(rby - lty, 0.0f);
                    float inter = wx * wy;
                    float den = ((car[m] + par) - inter) + 1e-9f;  // victim area first (ref order)
                    if (inter / den > 0.5f) {
                        if (lane < 32) atomicOr(&kb0[m], 1u << lane);
                        else           atomicOr(&kb1[m], 1u << (lane - 32));
                    }
                }
            }
            __syncthreads();

            if (tid < 64) {
                const int ci = base + lane;
                const bool have = ci < trusted;
                const u64 kbm = ((u64)kb1[lane] << 32) | kb0[lane];
                const u64 ps = ((u64)psupm[1] << 32) | psupm[0];
                const bool alive0 = have && !((ps >> lane) & 1);
                // fixpoint of greedy recurrence (unique; converges <= chain depth)
                u64 accm = __ballot(alive0);
                for (int it = 0; it < 64; ++it) {
                    u64 nm = __ballot(alive0 && ((kbm & accm) == 0ull));
                    if (nm == accm) break;
                    accm = nm;
                }
                const bool a = (accm >> lane) & 1;
                const int rank = (int)__popcll(accm & ((1ull << lane) - 1ull));
                const int rem = MAXDET - kcur;
                if (a && rank < rem) {
                    const int slot = kcur + rank;
                    aX1[slot] = px1; aY1[slot] = py1; aX2[slot] = px2; aY2[slot] = py2; aAr[slot] = par;
                    const u64 ky = keys[ci];
                    selp[slot] = __uint_as_float((u32)(ky >> 32) ^ 0x80000000u);
                    idxp[slot] = (int)(~(u32)ky);
                }
                if (lane == 0) {
                    const int cnt = (int)__popcll(accm);
                    ctrl[5] = kcur + (cnt < rem ? cnt : rem);
                }
            }
            __syncthreads();
        }

        if (tid == 0) ubk = keys[trusted - 1];
        __syncthreads();
        if (ctrl[5] >= MAXDET || cumTotal - trusted <= 0) break;
    }

    const int kfin = ctrl[5];
    for (int f = kfin + tid; f < MAXDET; f += BLKN) { selp[f] = NEGV; idxp[f] = 0; }
}

// ---------------- Kernel 2: per-image global top-300 via 2-level select + gather ----------------
#define OFF_B3D (NB * MAXDET * 4)
#define OFF_SC  (OFF_B3D + NB * MAXDET * 16)
#define OFF_LAB (OFF_SC + NB * MAXDET)

__global__ __launch_bounds__(512, 1) void topk_kernel(
    const float4* __restrict__ boxes,
    const float*  __restrict__ b3d,
    const float*  __restrict__ sel_ws,
    const int*    __restrict__ idx_ws,
    float* __restrict__ out,
    int n)
{
    const int b = blockIdx.x;
    const int tid = threadIdx.x;
    const int lane = tid & 63;
    const int wv = tid >> 6;
    const int M = NCLS * MAXDET;              // 6000

    __shared__ u64  kall[NCLS * MAXDET];      // 48KB
    __shared__ u32  h1[512];
    __shared__ u64  keys[512];
    __shared__ int  wts[8], ews[8];
    __shared__ int  ctrl[8];                  // 0:B1 1:cA1 2:total 3:hiCnt 4:loCnt 5:B2 6:cA2
    __shared__ int  outA[MAXDET];

    const float* sp = sel_ws + b * M;
    for (int f = tid; f < M; f += 512) {
        float v = sp[f];
        kall[f] = (v > 0.05f) ? packkey(v, f) : 0ull;
    }
    h1[tid] = 0;
    keys[tid] = 0;
    if (tid > 0 && tid < 8) ctrl[tid] = 0;
    if (tid == 0) { ctrl[0] = -1; ctrl[5] = -1; }
    __syncthreads();

    // level-1 hist (512 bins on score)
    for (int f = tid; f < M; f += 512) {
        u64 k = kall[f];
        if (k) {
            float s = __uint_as_float((u32)(k >> 32) ^ 0x80000000u);
            atomicAdd(&h1[binfull(s) >> 9], 1u);
        }
    }
    __syncthreads();
    {
        const int h = (int)h1[tid];
        int acc = h;
#pragma unroll
        for (int d = 1; d < 64; d <<= 1) { int o = __shfl_down(acc, d); if (lane + d < 64) acc += o; }
        if (lane == 0) wts[wv] = acc;
        __syncthreads();
        if (tid < 8) { int e = 0; for (int w = tid + 1; w < 8; ++w) e += wts[w]; ews[tid] = e; }
        __syncthreads();
        const int S = acc + ews[wv];
        if (S >= MAXDET && (S - h) < MAXDET) { ctrl[0] = tid; ctrl[1] = S - h; }
        if (tid == 0) ctrl[2] = S;
    }
    __syncthreads();
    const int B1 = ctrl[0];
    const int cA1 = ctrl[1];

    // level-2 hist (512 sub-bins within bin B1)
    h1[tid] = 0;
    __syncthreads();
    if (B1 >= 0) {
        for (int f = tid; f < M; f += 512) {
            u64 k = kall[f];
            if (k) {
                float s = __uint_as_float((u32)(k >> 32) ^ 0x80000000u);
                int full = binfull(s);
                if ((full >> 9) == B1) atomicAdd(&h1[full & 511], 1u);
            }
        }
    }
    __syncthreads();
    const int KT2 = MAXDET - cA1;             // >= 1 when B1 >= 0
    {
        const int h = (int)h1[tid];
        int acc = h;
#pragma unroll
        for (int d = 1; d < 64; d <<= 1) { int o = __shfl_down(acc, d); if (lane + d < 64) acc += o; }
        if (lane == 0) wts[wv] = acc;
        __syncthreads();
        if (tid < 8) { int e = 0; for (int w = tid + 1; w < 8; ++w) e += wts[w]; ews[tid] = e; }
        __syncthreads();
        const int S = acc + ews[wv];
        if (B1 >= 0 && S >= KT2 && (S - h) < KT2) { ctrl[5] = tid; ctrl[6] = S - h; }
    }
    __syncthreads();
    const int B2 = ctrl[5];
    const int cA2 = ctrl[6];

    // collect
    for (int f = tid; f < M; f += 512) {
        u64 k = kall[f];
        if (k) {
            float s = __uint_as_float((u32)(k >> 32) ^ 0x80000000u);
            int full = binfull(s);
            int bkt = full >> 9, sub = full & 511;
            bool hi = (B1 < 0) || (bkt > B1) || (bkt == B1 && sub > B2);
            bool lo = (B1 >= 0) && (bkt == B1) && (sub == B2);
            if (hi) { int slot = atomicAdd(&ctrl[3], 1); if (slot < 512) keys[slot] = k; }
            else if (lo) { int p = atomicAdd(&ctrl[4], 1); int pos = 511 - p; if (pos >= cA1 + cA2) keys[pos] = k; }
        }
    }
    __syncthreads();
    const bool dropped = (ctrl[3] + ctrl[4]) > 512;

    if (!dropped) {
        // bitonic sort desc over 512 (256 comparators)
        for (int k2 = 2; k2 <= 512; k2 <<= 1) {
            for (int jj = k2 >> 1; jj > 0; jj >>= 1) {
                if (tid < 256) {
                    const int i = ((tid & ~(jj - 1)) << 1) | (tid & (jj - 1));
                    const int ix = i | jj;
                    u64 a = keys[i], v = keys[ix];
                    const bool desc = ((i & k2) == 0);
                    if ((a < v) == desc) { keys[i] = v; keys[ix] = a; }
                }
                __syncthreads();
            }
        }
    } else {
        // exact fallback: 20-way sequential merge on wave 0 (rare)
        if (tid < 64) {
            int pos = 0;
            for (int k = 0; k < MAXDET; ++k) {
                u64 key = 0;
                if (lane < NCLS && pos < MAXDET) key = kall[lane * MAXDET + pos];
                u64 r = wredmax64(key);
                if (r != 0) {
                    u64 bal = __ballot(key == r);
                    int w = __ffsll((long long)bal) - 1;
                    if (lane == w) pos++;
                }
                if (lane == 0) keys[k] = r;
            }
        }
        __syncthreads();
    }

    // gather + write (keys[k]==0 -> invalid row)
    for (int k = tid; k < MAXDET; k += 512) {
        const u64 kk = keys[k];
        const bool ok = kk != 0;
        const int flat = (int)(~(u32)kk);
        const float sc = __uint_as_float((u32)(kk >> 32) ^ 0x80000000u);
        const int a = ok ? idx_ws[b * M + flat] : -1;
        const int cc = flat / MAXDET;
        float4 bx = make_float4(-1.f, -1.f, -1.f, -1.f);
        if (ok) bx = boxes[(long)b * n + a];
        out[(long)b * MAXDET * 4 + k * 4 + 0] = bx.x;
        out[(long)b * MAXDET * 4 + k * 4 + 1] = bx.y;
        out[(long)b * MAXDET * 4 + k * 4 + 2] = bx.z;
        out[(long)b * MAXDET * 4 + k * 4 + 3] = bx.w;
        out[OFF_SC  + (long)b * MAXDET + k] = ok ? sc : -1.0f;
        out[OFF_LAB + (long)b * MAXDET + k] = ok ? (float)cc : -1.0f;
        outA[k] = a;
    }
    __syncthreads();
    for (int q = tid; q < MAXDET * 16; q += 512) {
        const int k = q >> 4;
        const int a = outA[k];
        out[OFF_B3D + (long)b * MAXDET * 16 + q] = (a >= 0) ? b3d[((long)b * n + a) * 16 + (q & 15)] : -1.0f;
    }
}

extern "C" void kernel_launch(void* const* d_in, const int* in_sizes, int n_in,
                              void* d_out, int out_size, void* d_ws, size_t ws_size,
                              hipStream_t stream)
{
    const float* boxes = (const float*)d_in[0];   // [8, N, 4]
    const float* b3d   = (const float*)d_in[1];   // [8, N, 16]
    const float* cls   = (const float*)d_in[2];   // [8, N, 20]
    float* out = (float*)d_out;

    const int n = in_sizes[0] / (NB * 4);         // 49104

    const size_t needT = (size_t)NB * NCLS * n * sizeof(float);     // ~31.4MB
    const size_t selB  = (size_t)NB * NCLS * MAXDET * sizeof(float);

    if (ws_size >= needT + 2 * selB) {
        float* clsT   = (float*)d_ws;
        float* sel_ws = (float*)((char*)d_ws + needT);
        int*   idx_ws = (int*)((char*)d_ws + needT + selB);
        hipLaunchKernelGGL(transpose_cls_kernel, dim3((n + 255) / 256, NB), dim3(256), 0, stream,
                           cls, clsT, n);
        hipLaunchKernelGGL((nms_kernel<true>), dim3(NB * NCLS), dim3(BLKN), 0, stream,
                           (const float4*)boxes, cls, clsT, sel_ws, idx_ws, n);
        hipLaunchKernelGGL(topk_kernel, dim3(NB), dim3(512), 0, stream,
                           (const float4*)boxes, b3d, sel_ws, idx_ws, out, n);
    } else {
        float* sel_ws = (float*)d_ws;
        int*   idx_ws = (int*)((char*)d_ws + selB);
        hipLaunchKernelGGL((nms_kernel<false>), dim3(NB * NCLS), dim3(BLKN), 0, stream,
                           (const float4*)boxes, cls, nullptr, sel_ws, idx_ws, n);
        hipLaunchKernelGGL(topk_kernel, dim3(NB), dim3(512), 0, stream,
                           (const float4*)boxes, b3d, sel_ws, idx_ws, out, n);
    }
}